// Round 5
// baseline (6951.624 us; speedup 1.0000x reference)
//
#include <hip/hip_runtime.h>
#include <math.h>

#define VOCAB 50257
#define HID   1024
#define G4    4096
#define LZD   128
#define CDD   32
#define SEQ   256
#define NWG   128
#define WSTR  1032   // 1024 + 8 pad -> bank-conflict-free matvec reads

// ---------------- helpers ----------------
__device__ __forceinline__ float sigm(float x){ return 1.0f/(1.0f+expf(-x)); }

__device__ __forceinline__ float agent_ldf(const float* p){
  return __hip_atomic_load(p, __ATOMIC_RELAXED, __HIP_MEMORY_SCOPE_AGENT);
}
__device__ __forceinline__ void agent_stf(float* p, float v){
  __hip_atomic_store(p, v, __ATOMIC_RELAXED, __HIP_MEMORY_SCOPE_AGENT);
}
__device__ __forceinline__ int agent_ldi_acq(const int* p){
  return __hip_atomic_load(p, __ATOMIC_ACQUIRE, __HIP_MEMORY_SCOPE_AGENT);
}
__device__ __forceinline__ void agent_sti_rel(int* p, int v){
  __hip_atomic_store(p, v, __ATOMIC_RELEASE, __HIP_MEMORY_SCOPE_AGENT);
}

// JAX uniform(-0.99999994,1) bits -> sqrt(2)*erfinv (Giles poly, == XLA f32 ErfInv)
__device__ __forceinline__ float eps_from_bits(unsigned bits){
  float f = __uint_as_float((bits>>9) | 0x3F800000u) - 1.0f;   // [0,1)
  const float MINV = -0.99999994f;                             // nextafter(-1,0)
  float u = fmaxf(MINV, f*2.0f + MINV);                        // (hi-lo) rounds to 2.0f
  float w = -log1pf(-u*u);
  float p;
  if(w < 5.0f){
    w -= 2.5f;
    p =  2.81022636e-08f;
    p = fmaf(p,w, 3.43273939e-07f);
    p = fmaf(p,w,-3.5233877e-06f);
    p = fmaf(p,w,-4.39150654e-06f);
    p = fmaf(p,w, 0.00021858087f);
    p = fmaf(p,w,-0.00125372503f);
    p = fmaf(p,w,-0.00417768164f);
    p = fmaf(p,w, 0.246640727f);
    p = fmaf(p,w, 1.50140941f);
  }else{
    w = sqrtf(w) - 3.0f;
    p = -0.000200214257f;
    p = fmaf(p,w, 0.000100950558f);
    p = fmaf(p,w, 0.00134934322f);
    p = fmaf(p,w,-0.00367342844f);
    p = fmaf(p,w, 0.00573950773f);
    p = fmaf(p,w,-0.0076224613f);
    p = fmaf(p,w, 0.00943887047f);
    p = fmaf(p,w, 1.00167406f);
    p = fmaf(p,w, 2.83297682f);
  }
  return 1.4142135623730951f * (p*u);
}

// ---------------- prep: gathers + flag reset ----------------
__global__ __launch_bounds__(256) void vae_embed(
    const int* __restrict__ tok, const float* __restrict__ enc_emb,
    const float* __restrict__ dec_emb,
    float* __restrict__ xenc, float* __restrict__ xdec, int* __restrict__ flags)
{
  const int b = blockIdx.x, tid = threadIdx.x;
  if(b == SEQ){ if(tid < NWG) flags[tid] = 0; return; }   // re-init barrier flags every launch
  const int te = tok[b];
  const int td = (b==0) ? 0 : tok[b-1];                   // SOS = 0
  float4 v = *(const float4*)(enc_emb + (size_t)te*HID + tid*4);
  *(float4*)(xenc + (size_t)b*HID + tid*4) = v;
  float4 u = *(const float4*)(dec_emb + (size_t)td*HID + tid*4);
  u.x=fmaxf(u.x,0.f); u.y=fmaxf(u.y,0.f); u.z=fmaxf(u.z,0.f); u.w=fmaxf(u.w,0.f);
  *(float4*)(xdec + (size_t)b*HID + tid*4) = u;
}

// ---------------- fp32 GEMM: C[M,N] = A[M,K] @ B[N,K]^T + b1 (+ b2) ----------------
__global__ __launch_bounds__(256) void gemm_nt_bias(
    const float* __restrict__ A, const float* __restrict__ B,
    const float* __restrict__ bias1, const float* __restrict__ bias2,
    float* __restrict__ C, int K, int N)
{
  __shared__ float As[16*68];
  __shared__ float Bs[16*68];
  const int tid = threadIdx.x;
  const int bn = blockIdx.x<<6, bm = blockIdx.y<<6;
  const int lr = tid>>2, lc4 = (tid&3)<<2;
  const int tx = tid&15, ty = tid>>4;
  const float* Arow = A + (size_t)(bm+lr)*K + lc4;
  const float* Brow = B + (size_t)(bn+lr)*K + lc4;
  const bool bvalid = (bn+lr) < N;
  float acc[4][4] = {};
  for(int kt=0; kt<K; kt+=16){
    float4 av = *(const float4*)(Arow + kt);
    float4 bv = bvalid ? *(const float4*)(Brow + kt) : make_float4(0.f,0.f,0.f,0.f);
    __syncthreads();
    As[(lc4+0)*68+lr]=av.x; As[(lc4+1)*68+lr]=av.y; As[(lc4+2)*68+lr]=av.z; As[(lc4+3)*68+lr]=av.w;
    Bs[(lc4+0)*68+lr]=bv.x; Bs[(lc4+1)*68+lr]=bv.y; Bs[(lc4+2)*68+lr]=bv.z; Bs[(lc4+3)*68+lr]=bv.w;
    __syncthreads();
#pragma unroll
    for(int k=0;k<16;++k){
      float4 a = *(const float4*)(As + k*68 + (ty<<2));
      float4 b = *(const float4*)(Bs + k*68 + (tx<<2));
      float a4[4] = {a.x,a.y,a.z,a.w};
      float b4[4] = {b.x,b.y,b.z,b.w};
#pragma unroll
      for(int i=0;i<4;++i)
#pragma unroll
        for(int j=0;j<4;++j)
          acc[i][j] = fmaf(a4[i], b4[j], acc[i][j]);
    }
  }
  const int n0 = bn + (tx<<2);
#pragma unroll
  for(int i=0;i<4;++i){
    const int m = bm + (ty<<2) + i;
#pragma unroll
    for(int j=0;j<4;++j){
      const int n = n0+j;
      if(n < N)
        C[(size_t)m*N + n] = acc[i][j] + bias1[n] + (bias2 ? bias2[n] : 0.f);
    }
  }
}

// ---------------- persistent scan: enc LSTM -> latent -> dec LSTM ----------------
__global__ __launch_bounds__(256,1) void vae_scan(
    const float* __restrict__ enc_Whh, const float* __restrict__ dec_Whh,
    const float* __restrict__ pre_enc, const float* __restrict__ pre_dec,
    const float* __restrict__ h0in, const float* __restrict__ c0in,
    const float* __restrict__ ccond,
    const float* __restrict__ mean_W, const float* __restrict__ mean_b,
    const float* __restrict__ logvar_W, const float* __restrict__ logvar_b,
    const float* __restrict__ lc_W, const float* __restrict__ lc_b,
    float* __restrict__ hbuf, float* __restrict__ Hdec,
    float* __restrict__ meanlv, float* __restrict__ latcat, int* __restrict__ flags,
    float* __restrict__ out_mean, float* __restrict__ out_logvar)
{
  // 32 W_hh rows (4 gates x 8 hidden units) per WG, fp32, padded stride
  __shared__ float W_lds[32*WSTR];   // 132 KB
  __shared__ float h_lds[HID];
  __shared__ float lat_lds[LZD+CDD];
  __shared__ float gbuf[32];
  __shared__ float redb[4];
  __shared__ float cst[8];

  const int w = blockIdx.x, tid = threadIdx.x;
  const int r = tid>>3, l = tid&7;   // 8 threads per gate-row

  // ---- load encoder W_hh slice into LDS ----
  for(int gate=0; gate<4; ++gate){
    const float* src = enc_Whh + ((size_t)(gate*HID + 8*w))*HID;
#pragma unroll
    for(int it=0; it<8; ++it){
      float4 v = *(const float4*)(src + it*HID + tid*4);
      *(float4*)(&W_lds[(gate*8+it)*WSTR + tid*4]) = v;
    }
  }
  if(tid<8){
    cst[tid] = c0in[8*w+tid];
    agent_stf(&hbuf[8*w+tid], h0in[8*w+tid]);   // epoch 0 -> buffer 0
  }
  __syncthreads();
  if(tid==0){ __threadfence(); agent_sti_rel(&flags[w], 1); }

  // ---- encoder scan ----
  for(int t=0; t<SEQ; ++t){
    if(tid<NWG){ while(agent_ldi_acq(&flags[tid]) < t+1) __builtin_amdgcn_s_sleep(1); }
    __syncthreads();
    const float* hb = hbuf + (t&1)*HID;
    for(int i=tid;i<HID;i+=256) h_lds[i] = agent_ldf(hb+i);
    __syncthreads();
    float a0=0,a1=0,a2=0,a3=0;
    {
      const float* wr = W_lds + r*WSTR + l*4;
      const float* hr = h_lds + l*4;
#pragma unroll 8
      for(int kk=0; kk<32; ++kk){
        float4 wv = *(const float4*)(wr + kk*32);
        float4 hv = *(const float4*)(hr + kk*32);
        a0 = fmaf(wv.x, hv.x, a0);
        a1 = fmaf(wv.y, hv.y, a1);
        a2 = fmaf(wv.z, hv.z, a2);
        a3 = fmaf(wv.w, hv.w, a3);
      }
    }
    float acc = (a0+a1)+(a2+a3);
    acc += __shfl_xor(acc,1); acc += __shfl_xor(acc,2); acc += __shfl_xor(acc,4);
    if(l==0) gbuf[r] = acc + pre_enc[(size_t)t*G4 + (r>>3)*HID + 8*w + (r&7)];
    __syncthreads();
    if(tid<8){
      float gi=gbuf[tid], gf=gbuf[8+tid], gg=gbuf[16+tid], go=gbuf[24+tid];
      float c = cst[tid];
      float cn = sigm(gf)*c + sigm(gi)*tanhf(gg);
      float hn = sigm(go)*tanhf(cn);
      cst[tid] = cn;
      agent_stf(&hbuf[((t+1)&1)*HID + 8*w + tid], hn);
    }
    __syncthreads();
    if(tid==0){ __threadfence(); agent_sti_rel(&flags[w], t+2); }
  }

  // ---- mean / logvar: WG w computes rows 2w, 2w+1 of [mean;logvar] ----
  if(tid<NWG){ while(agent_ldi_acq(&flags[tid]) < SEQ+1) __builtin_amdgcn_s_sleep(1); }
  __syncthreads();
  for(int i=tid;i<HID;i+=256) h_lds[i] = agent_ldf(hbuf + i);  // epoch 256 -> buffer 0
  __syncthreads();
  for(int rr=0; rr<2; ++rr){
    int row = 2*w + rr;
    const float* Wrow; float bias;
    if(row < LZD){ Wrow = mean_W   + (size_t)row*HID;       bias = mean_b[row]; }
    else         { Wrow = logvar_W + (size_t)(row-LZD)*HID; bias = logvar_b[row-LZD]; }
    float4 hv = *(const float4*)(h_lds + tid*4);
    float4 wv = *(const float4*)(Wrow + tid*4);
    float p = hv.x*wv.x + hv.y*wv.y + hv.z*wv.z + hv.w*wv.w;
    p += __shfl_xor(p,1); p += __shfl_xor(p,2); p += __shfl_xor(p,4);
    p += __shfl_xor(p,8); p += __shfl_xor(p,16); p += __shfl_xor(p,32);
    if((tid&63)==0) redb[tid>>6] = p;
    __syncthreads();
    if(tid==0){
      float s = redb[0]+redb[1]+redb[2]+redb[3] + bias;
      agent_stf(&meanlv[row], s);
      if(row < LZD) out_mean[row] = s; else out_logvar[row-LZD] = s;
    }
    __syncthreads();
  }
  if(tid==0){ __threadfence(); agent_sti_rel(&flags[w], SEQ+2); }   // 258

  // ---- WG0: partitionable-threefry eps + latent ----
  if(w==0){
    if(tid<NWG){ while(agent_ldi_acq(&flags[tid]) < SEQ+2) __builtin_amdgcn_s_sleep(1); }
    __syncthreads();
    if(tid < LZD){
      // jax_threefry_partitionable=True: per element i, threefry2x32((0,1), (0,i)),
      // 32-bit output = word0 ^ word1
      unsigned x0 = 0u, x1 = (unsigned)tid;
      const unsigned ks[3] = {0u, 1u, 0x1BD11BDAu ^ 0u ^ 1u};   // key(1)
      x0 += ks[0]; x1 += ks[1];
      const int RA[4] = {13,15,26,6}, RB[4] = {17,29,16,24};
#pragma unroll
      for(int g=0; g<5; ++g){
        const int* R = (g&1) ? RB : RA;
#pragma unroll
        for(int q=0;q<4;++q){
          x0 += x1;
          x1 = (x1 << R[q]) | (x1 >> (32-R[q]));
          x1 ^= x0;
        }
        x0 += ks[(g+1)%3];
        x1 += ks[(g+2)%3] + (unsigned)(g+1);
      }
      h_lds[tid] = eps_from_bits(x0 ^ x1);
    }
    __syncthreads();
    if(tid < LZD){
      float mn = agent_ldf(&meanlv[tid]);
      float lv = agent_ldf(&meanlv[LZD+tid]);
      agent_stf(&latcat[tid], fmaf(h_lds[tid], expf(0.5f*lv), mn));
    } else if(tid < LZD+CDD){
      agent_stf(&latcat[tid], ccond[tid-LZD]);
    }
    __syncthreads();
    if(tid==0){ __threadfence(); agent_sti_rel(&flags[0], SEQ+3); }  // 259
  }

  // ---- switch to decoder weights, init c=0, wait for latent ----
  for(int gate=0; gate<4; ++gate){
    const float* src = dec_Whh + ((size_t)(gate*HID + 8*w))*HID;
#pragma unroll
    for(int it=0; it<8; ++it){
      float4 v = *(const float4*)(src + it*HID + tid*4);
      *(float4*)(&W_lds[(gate*8+it)*WSTR + tid*4]) = v;
    }
  }
  if(tid<8) cst[tid] = 0.0f;
  __syncthreads();
  if(tid==0){ while(agent_ldi_acq(&flags[0]) < SEQ+3) __builtin_amdgcn_s_sleep(1); }
  __syncthreads();
  for(int i=tid;i<LZD+CDD;i+=256) lat_lds[i] = agent_ldf(&latcat[i]);
  __syncthreads();
  if(tid<8){
    int j = 8*w + tid;
    float s = lc_b[j];
    const float* wr = lc_W + (size_t)j*(LZD+CDD);
#pragma unroll 8
    for(int k=0;k<LZD+CDD;++k) s = fmaf(lat_lds[k], wr[k], s);
    agent_stf(&hbuf[j], s);   // dec epoch 0 -> buffer 0
  }
  __syncthreads();
  if(tid==0){ __threadfence(); agent_sti_rel(&flags[w], SEQ+4); }  // 260

  // ---- decoder scan ----
  const int DB = SEQ+4;
  for(int t=0; t<SEQ; ++t){
    if(tid<NWG){ while(agent_ldi_acq(&flags[tid]) < DB+t) __builtin_amdgcn_s_sleep(1); }
    __syncthreads();
    const float* hb = hbuf + (t&1)*HID;
    for(int i=tid;i<HID;i+=256) h_lds[i] = agent_ldf(hb+i);
    __syncthreads();
    float a0=0,a1=0,a2=0,a3=0;
    {
      const float* wr = W_lds + r*WSTR + l*4;
      const float* hr = h_lds + l*4;
#pragma unroll 8
      for(int kk=0; kk<32; ++kk){
        float4 wv = *(const float4*)(wr + kk*32);
        float4 hv = *(const float4*)(hr + kk*32);
        a0 = fmaf(wv.x, hv.x, a0);
        a1 = fmaf(wv.y, hv.y, a1);
        a2 = fmaf(wv.z, hv.z, a2);
        a3 = fmaf(wv.w, hv.w, a3);
      }
    }
    float acc = (a0+a1)+(a2+a3);
    acc += __shfl_xor(acc,1); acc += __shfl_xor(acc,2); acc += __shfl_xor(acc,4);
    if(l==0) gbuf[r] = acc + pre_dec[(size_t)t*G4 + (r>>3)*HID + 8*w + (r&7)];
    __syncthreads();
    if(tid<8){
      float gi=gbuf[tid], gf=gbuf[8+tid], gg=gbuf[16+tid], go=gbuf[24+tid];
      float c = cst[tid];
      float cn = sigm(gf)*c + sigm(gi)*tanhf(gg);
      float hn = sigm(go)*tanhf(cn);
      cst[tid] = cn;
      Hdec[(size_t)t*HID + 8*w + tid] = hn;   // consumed by logits GEMM
      agent_stf(&hbuf[((t+1)&1)*HID + 8*w + tid], hn);
    }
    __syncthreads();
    if(tid==0){ __threadfence(); agent_sti_rel(&flags[w], DB+t+1); }
  }
}

// ---------------- in-place log_softmax + first-index argmax ----------------
__global__ __launch_bounds__(256) void softmax_argmax(float* __restrict__ dist,
                                                      float* __restrict__ outTok)
{
  __shared__ float wm[4]; __shared__ int wi[4];
  __shared__ float s_max; __shared__ int s_idx; __shared__ float s_lz;
  const int t = blockIdx.x, tid = threadIdx.x;
  float* row = dist + (size_t)t*VOCAB;
  float m = -INFINITY; int idx = VOCAB;
  for(int i=tid; i<VOCAB; i+=256){
    float v = row[i];
    if(v > m){ m = v; idx = i; }
  }
  for(int d=1; d<64; d<<=1){
    float m2 = __shfl_xor(m, d); int i2 = __shfl_xor(idx, d);
    if(m2 > m || (m2 == m && i2 < idx)){ m = m2; idx = i2; }
  }
  if((tid&63)==0){ wm[tid>>6]=m; wi[tid>>6]=idx; }
  __syncthreads();
  if(tid==0){
    float mm = wm[0]; int ii = wi[0];
    for(int q=1;q<4;++q) if(wm[q]>mm || (wm[q]==mm && wi[q]<ii)){ mm=wm[q]; ii=wi[q]; }
    s_max = mm; s_idx = ii;
  }
  __syncthreads();
  const float M = s_max;
  float s = 0.f;
  for(int i=tid; i<VOCAB; i+=256) s += expf(row[i] - M);
  for(int d=1; d<64; d<<=1) s += __shfl_xor(s, d);
  if((tid&63)==0) wm[tid>>6] = s;
  __syncthreads();
  if(tid==0) s_lz = M + logf(wm[0]+wm[1]+wm[2]+wm[3]);
  __syncthreads();
  const float lz = s_lz;
  for(int i=tid; i<VOCAB; i+=256) row[i] -= lz;
  if(tid==0) outTok[t] = (float)s_idx;
}

// ---------------- launch ----------------
extern "C" void kernel_launch(void* const* d_in, const int* in_sizes, int n_in,
                              void* d_out, int out_size, void* d_ws, size_t ws_size,
                              hipStream_t stream)
{
  (void)in_sizes; (void)n_in; (void)out_size; (void)ws_size;
  const int*   tok      = (const int*)  d_in[0];
  const float* h0       = (const float*)d_in[1];
  const float* c0       = (const float*)d_in[2];
  const float* ccond    = (const float*)d_in[3];
  // d_in[4] = use_teacher_forcing (unused by reference body)
  const float* enc_emb  = (const float*)d_in[5];
  const float* enc_Wih  = (const float*)d_in[6];
  const float* enc_Whh  = (const float*)d_in[7];
  const float* enc_bih  = (const float*)d_in[8];
  const float* enc_bhh  = (const float*)d_in[9];
  const float* dec_emb  = (const float*)d_in[10];
  const float* dec_Wih  = (const float*)d_in[11];
  const float* dec_Whh  = (const float*)d_in[12];
  const float* dec_bih  = (const float*)d_in[13];
  const float* dec_bhh  = (const float*)d_in[14];
  const float* out_W    = (const float*)d_in[15];
  const float* out_b    = (const float*)d_in[16];
  const float* mean_W   = (const float*)d_in[17];
  const float* mean_b   = (const float*)d_in[18];
  const float* logvar_W = (const float*)d_in[19];
  const float* logvar_b = (const float*)d_in[20];
  const float* lc_W     = (const float*)d_in[21];
  const float* lc_b     = (const float*)d_in[22];

  float* ws      = (float*)d_ws;
  float* xenc    = ws;                       // 256*1024
  float* xdec    = xenc + SEQ*HID;           // 256*1024
  float* pre_enc = xdec + SEQ*HID;           // 256*4096
  float* pre_dec = pre_enc + (size_t)SEQ*G4; // 256*4096
  float* hbuf    = pre_dec + (size_t)SEQ*G4; // 2*1024
  float* Hdec    = hbuf + 2*HID;             // 256*1024
  float* meanlv  = Hdec + (size_t)SEQ*HID;   // 256
  float* latcat  = meanlv + 2*LZD;           // 160 (+pad)
  int*   flags   = (int*)(latcat + 192);     // 128 ints
  // total ~11.6 MB of ws

  float* out      = (float*)d_out;
  float* outTok   = out;                          // [256] tokens (as f32)
  float* dist     = out + SEQ;                    // [256,50257] log-softmax
  float* out_mean = dist + (size_t)SEQ*VOCAB;     // [128]
  float* out_lv   = out_mean + LZD;               // [128]

  hipLaunchKernelGGL(vae_embed, dim3(SEQ+1), dim3(256), 0, stream,
                     tok, enc_emb, dec_emb, xenc, xdec, flags);
  hipLaunchKernelGGL(gemm_nt_bias, dim3(G4/64, SEQ/64), dim3(256), 0, stream,
                     xenc, enc_Wih, enc_bih, enc_bhh, pre_enc, HID, G4);
  hipLaunchKernelGGL(gemm_nt_bias, dim3(G4/64, SEQ/64), dim3(256), 0, stream,
                     xdec, dec_Wih, dec_bih, dec_bhh, pre_dec, HID, G4);
  hipLaunchKernelGGL(vae_scan, dim3(NWG), dim3(256), 0, stream,
                     enc_Whh, dec_Whh, pre_enc, pre_dec, h0, c0, ccond,
                     mean_W, mean_b, logvar_W, logvar_b, lc_W, lc_b,
                     hbuf, Hdec, meanlv, latcat, flags, out_mean, out_lv);
  hipLaunchKernelGGL(gemm_nt_bias, dim3((VOCAB+63)/64, SEQ/64), dim3(256), 0, stream,
                     Hdec, out_W, out_b, (const float*)nullptr, dist, HID, VOCAB);
  hipLaunchKernelGGL(softmax_argmax, dim3(SEQ), dim3(256), 0, stream, dist, outTok);
}

// Round 6
// 2325.860 us; speedup vs baseline: 2.9888x; 2.9888x over previous
//
#include <hip/hip_runtime.h>
#include <math.h>

#define VOCAB 50257
#define HID   1024
#define G4    4096
#define LZD   128
#define CDD   32
#define SEQ   256
#define NWG   256          // scan workgroups: WG q owns h-units 4q..4q+3
#define WSTR  1032         // 1024 + 8 pad
#define DECTAG 300u        // decoder tag base (> encoder max 256)

typedef unsigned long long ull;

// ---------------- helpers ----------------
__device__ __forceinline__ float sigm(float x){ return 1.0f/(1.0f+expf(-x)); }

// tagged-word protocol: one 64-bit relaxed agent atomic = (tag<<32)|float_bits.
// Data + readiness in one word -> no fences, no L2 writebacks.
__device__ __forceinline__ void pub_val(ull* p, float x, unsigned tag){
  ull v = ((ull)tag<<32) | (ull)__float_as_uint(x);
  __hip_atomic_store(p, v, __ATOMIC_RELAXED, __HIP_MEMORY_SCOPE_AGENT);
}
__device__ __forceinline__ float poll_val(ull* p, unsigned tag){
  ull v = __hip_atomic_load(p, __ATOMIC_RELAXED, __HIP_MEMORY_SCOPE_AGENT);
  while((unsigned)(v>>32) != tag){
    __builtin_amdgcn_s_sleep(1);
    v = __hip_atomic_load(p, __ATOMIC_RELAXED, __HIP_MEMORY_SCOPE_AGENT);
  }
  return __uint_as_float((unsigned)v);
}

// JAX uniform bits -> sqrt(2)*erfinv (Giles poly, == XLA f32 ErfInv)
__device__ __forceinline__ float eps_from_bits(unsigned bits){
  float f = __uint_as_float((bits>>9) | 0x3F800000u) - 1.0f;
  const float MINV = -0.99999994f;
  float u = fmaxf(MINV, f*2.0f + MINV);
  float w = -log1pf(-u*u);
  float p;
  if(w < 5.0f){
    w -= 2.5f;
    p =  2.81022636e-08f;
    p = fmaf(p,w, 3.43273939e-07f);
    p = fmaf(p,w,-3.5233877e-06f);
    p = fmaf(p,w,-4.39150654e-06f);
    p = fmaf(p,w, 0.00021858087f);
    p = fmaf(p,w,-0.00125372503f);
    p = fmaf(p,w,-0.00417768164f);
    p = fmaf(p,w, 0.246640727f);
    p = fmaf(p,w, 1.50140941f);
  }else{
    w = sqrtf(w) - 3.0f;
    p = -0.000200214257f;
    p = fmaf(p,w, 0.000100950558f);
    p = fmaf(p,w, 0.00134934322f);
    p = fmaf(p,w,-0.00367342844f);
    p = fmaf(p,w, 0.00573950773f);
    p = fmaf(p,w,-0.0076224613f);
    p = fmaf(p,w, 0.00943887047f);
    p = fmaf(p,w, 1.00167406f);
    p = fmaf(p,w, 2.83297682f);
  }
  return 1.4142135623730951f * (p*u);
}

// ---------------- prep: gathers + tag reset ----------------
__global__ __launch_bounds__(256) void vae_embed(
    const int* __restrict__ tok, const float* __restrict__ enc_emb,
    const float* __restrict__ dec_emb,
    float* __restrict__ xenc, float* __restrict__ xdec, ull* __restrict__ tags)
{
  const int b = blockIdx.x, tid = threadIdx.x;
  if(b == SEQ){
    // zero all tag words every launch (replay-deterministic): h 2*1024, mlv 256, lat 160
    for(int i=tid; i<2*HID+2*LZD+LZD+CDD; i+=256)
      __hip_atomic_store(&tags[i], 0ULL, __ATOMIC_RELAXED, __HIP_MEMORY_SCOPE_AGENT);
    return;
  }
  const int te = tok[b];
  const int td = (b==0) ? 0 : tok[b-1];                   // SOS = 0
  float4 v = *(const float4*)(enc_emb + (size_t)te*HID + tid*4);
  *(float4*)(xenc + (size_t)b*HID + tid*4) = v;
  float4 u = *(const float4*)(dec_emb + (size_t)td*HID + tid*4);
  u.x=fmaxf(u.x,0.f); u.y=fmaxf(u.y,0.f); u.z=fmaxf(u.z,0.f); u.w=fmaxf(u.w,0.f);
  *(float4*)(xdec + (size_t)b*HID + tid*4) = u;
}

// ---------------- fp32 GEMM: C[M,N] = A[M,K] @ B[N,K]^T + b1 (+ b2) ----------------
__global__ __launch_bounds__(256) void gemm_nt_bias(
    const float* __restrict__ A, const float* __restrict__ B,
    const float* __restrict__ bias1, const float* __restrict__ bias2,
    float* __restrict__ C, int K, int N)
{
  __shared__ float As[16*68];
  __shared__ float Bs[16*68];
  const int tid = threadIdx.x;
  const int bn = blockIdx.x<<6, bm = blockIdx.y<<6;
  const int lr = tid>>2, lc4 = (tid&3)<<2;
  const int tx = tid&15, ty = tid>>4;
  const float* Arow = A + (size_t)(bm+lr)*K + lc4;
  const float* Brow = B + (size_t)(bn+lr)*K + lc4;
  const bool bvalid = (bn+lr) < N;
  float acc[4][4] = {};
  for(int kt=0; kt<K; kt+=16){
    float4 av = *(const float4*)(Arow + kt);
    float4 bv = bvalid ? *(const float4*)(Brow + kt) : make_float4(0.f,0.f,0.f,0.f);
    __syncthreads();
    As[(lc4+0)*68+lr]=av.x; As[(lc4+1)*68+lr]=av.y; As[(lc4+2)*68+lr]=av.z; As[(lc4+3)*68+lr]=av.w;
    Bs[(lc4+0)*68+lr]=bv.x; Bs[(lc4+1)*68+lr]=bv.y; Bs[(lc4+2)*68+lr]=bv.z; Bs[(lc4+3)*68+lr]=bv.w;
    __syncthreads();
#pragma unroll
    for(int k=0;k<16;++k){
      float4 a = *(const float4*)(As + k*68 + (ty<<2));
      float4 b = *(const float4*)(Bs + k*68 + (tx<<2));
      float a4[4] = {a.x,a.y,a.z,a.w};
      float b4[4] = {b.x,b.y,b.z,b.w};
#pragma unroll
      for(int i=0;i<4;++i)
#pragma unroll
        for(int j=0;j<4;++j)
          acc[i][j] = fmaf(a4[i], b4[j], acc[i][j]);
    }
  }
  const int n0 = bn + (tx<<2);
#pragma unroll
  for(int i=0;i<4;++i){
    const int m = bm + (ty<<2) + i;
#pragma unroll
    for(int j=0;j<4;++j){
      const int n = n0+j;
      if(n < N)
        C[(size_t)m*N + n] = acc[i][j] + bias1[n] + (bias2 ? bias2[n] : 0.f);
    }
  }
}

// ---------------- persistent scan, fence-free tagged protocol ----------------
// 256 WGs x 256 thr. WG q owns h units 4q..4q+3 (16 gate rows in LDS, 66 KB).
// h_tag[2][1024]: slot t&1 holds h[t] with tag t (enc) / DECTAG+t (dec).
__global__ __launch_bounds__(256,1) void vae_scan(
    const float* __restrict__ enc_Whh, const float* __restrict__ dec_Whh,
    const float* __restrict__ pre_enc, const float* __restrict__ pre_dec,
    const float* __restrict__ h0in, const float* __restrict__ c0in,
    const float* __restrict__ ccond,
    const float* __restrict__ mean_W, const float* __restrict__ mean_b,
    const float* __restrict__ logvar_W, const float* __restrict__ logvar_b,
    const float* __restrict__ lc_W, const float* __restrict__ lc_b,
    ull* __restrict__ h_tag, ull* __restrict__ mlv_tag, ull* __restrict__ lat_tag,
    float* __restrict__ Hdec, float* __restrict__ out_mean, float* __restrict__ out_logvar)
{
  __shared__ float W_lds[16*WSTR];   // 66 KB
  __shared__ float h_lds[HID];
  __shared__ float lat_lds[LZD+CDD];
  __shared__ float sh_mlv[2*LZD];
  __shared__ float gbuf[16];
  __shared__ float redb[4];

  const int q = blockIdx.x, tid = threadIdx.x;
  const int r = tid>>4, l = tid&15;    // 16 rows x 16 lanes
  const int u4 = 4*q;

  // ---- load encoder W_hh rows {g*1024 + 4q + uu} ----
#pragma unroll
  for(int rr=0; rr<16; ++rr){
    const float* src = enc_Whh + ((size_t)((rr>>2)*HID + u4 + (rr&3)))*HID;
    float4 v = *(const float4*)(src + tid*4);
    *(float4*)(&W_lds[rr*WSTR + tid*4]) = v;
  }
  float creg = (tid<4) ? c0in[u4+tid] : 0.0f;
  __syncthreads();

  // ---- encoder scan ----
  for(int t=0; t<SEQ; ++t){
    if(t==0){
#pragma unroll
      for(int j=0;j<4;++j) h_lds[tid + j*256] = h0in[tid + j*256];
    }else{
      ull* slot = h_tag + (t&1)*HID;
#pragma unroll
      for(int j=0;j<4;++j) h_lds[tid + j*256] = poll_val(&slot[tid + j*256], (unsigned)t);
    }
    __syncthreads();
    float a0=0,a1=0,a2=0,a3=0;
    {
      const float* wr = W_lds + r*WSTR + l*4;
      const float* hr = h_lds + l*4;
#pragma unroll
      for(int kk=0; kk<16; ++kk){
        float4 wv = *(const float4*)(wr + kk*64);
        float4 hv = *(const float4*)(hr + kk*64);
        a0 = fmaf(wv.x, hv.x, a0);
        a1 = fmaf(wv.y, hv.y, a1);
        a2 = fmaf(wv.z, hv.z, a2);
        a3 = fmaf(wv.w, hv.w, a3);
      }
    }
    float acc = (a0+a1)+(a2+a3);
    acc += __shfl_xor(acc,1); acc += __shfl_xor(acc,2);
    acc += __shfl_xor(acc,4); acc += __shfl_xor(acc,8);
    if(l==0) gbuf[r] = acc + pre_enc[(size_t)t*G4 + (r>>2)*HID + u4 + (r&3)];
    __syncthreads();
    if(tid<4){
      float gi=gbuf[tid], gf=gbuf[4+tid], gg=gbuf[8+tid], go=gbuf[12+tid];
      float cn = sigm(gf)*creg + sigm(gi)*tanhf(gg);
      float hn = sigm(go)*tanhf(cn);
      creg = cn;
      pub_val(&h_tag[((t+1)&1)*HID + u4+tid], hn, (unsigned)(t+1));
    }
    __syncthreads();
  }

  // ---- mean/logvar: WG q computes row q of [mean;logvar]; h_enc = slot0 tag 256 ----
  {
    ull* slot = h_tag;   // slot 0
#pragma unroll
    for(int j=0;j<4;++j) h_lds[tid + j*256] = poll_val(&slot[tid + j*256], (unsigned)SEQ);
  }
  __syncthreads();
  {
    const float* Wrow = (q < LZD) ? (mean_W + (size_t)q*HID)
                                  : (logvar_W + (size_t)(q-LZD)*HID);
    const float bias = (q < LZD) ? mean_b[q] : logvar_b[q-LZD];
    float4 hv = *(const float4*)(h_lds + tid*4);
    float4 wv = *(const float4*)(Wrow + tid*4);
    float p = hv.x*wv.x + hv.y*wv.y + hv.z*wv.z + hv.w*wv.w;
    p += __shfl_xor(p,1); p += __shfl_xor(p,2); p += __shfl_xor(p,4);
    p += __shfl_xor(p,8); p += __shfl_xor(p,16); p += __shfl_xor(p,32);
    if((tid&63)==0) redb[tid>>6] = p;
    __syncthreads();
    if(tid==0){
      float s = redb[0]+redb[1]+redb[2]+redb[3] + bias;
      pub_val(&mlv_tag[q], s, 1u);
      if(q < LZD) out_mean[q] = s; else out_logvar[q-LZD] = s;
    }
  }

  // ---- WG0: partitionable-threefry eps + latent ----
  if(q==0){
    sh_mlv[tid] = poll_val(&mlv_tag[tid], 1u);
    __syncthreads();
    if(tid < LZD){
      unsigned x0 = 0u, x1 = (unsigned)tid;          // counter (0, i)
      const unsigned ks[3] = {0u, 1u, 0x1BD11BDAu ^ 0u ^ 1u};  // key(1)
      x0 += ks[0]; x1 += ks[1];
      const int RA[4] = {13,15,26,6}, RB[4] = {17,29,16,24};
#pragma unroll
      for(int g=0; g<5; ++g){
        const int* R = (g&1) ? RB : RA;
#pragma unroll
        for(int qq=0;qq<4;++qq){
          x0 += x1;
          x1 = (x1 << R[qq]) | (x1 >> (32-R[qq]));
          x1 ^= x0;
        }
        x0 += ks[(g+1)%3];
        x1 += ks[(g+2)%3] + (unsigned)(g+1);
      }
      float e = eps_from_bits(x0 ^ x1);
      pub_val(&lat_tag[tid], fmaf(e, expf(0.5f*sh_mlv[LZD+tid]), sh_mlv[tid]), 1u);
    } else if(tid < LZD+CDD){
      pub_val(&lat_tag[tid], ccond[tid-LZD], 1u);
    }
  }

  // ---- switch to decoder weights; dec_h0 = lc_W @ latcat + lc_b ----
  __syncthreads();
#pragma unroll
  for(int rr=0; rr<16; ++rr){
    const float* src = dec_Whh + ((size_t)((rr>>2)*HID + u4 + (rr&3)))*HID;
    float4 v = *(const float4*)(src + tid*4);
    *(float4*)(&W_lds[rr*WSTR + tid*4]) = v;
  }
  if(tid < LZD+CDD) lat_lds[tid] = poll_val(&lat_tag[tid], 1u);
  __syncthreads();
  if(tid<4){
    const int j = u4 + tid;
    float s = lc_b[j];
    const float* wr = lc_W + (size_t)j*(LZD+CDD);
#pragma unroll 8
    for(int k=0;k<LZD+CDD;++k) s = fmaf(lat_lds[k], wr[k], s);
    pub_val(&h_tag[j], s, DECTAG);   // slot 0
    creg = 0.0f;
  }
  __syncthreads();

  // ---- decoder scan ----
  for(int t=0; t<SEQ; ++t){
    {
      ull* slot = h_tag + (t&1)*HID;
#pragma unroll
      for(int j=0;j<4;++j) h_lds[tid + j*256] = poll_val(&slot[tid + j*256], DECTAG + (unsigned)t);
    }
    __syncthreads();
    float a0=0,a1=0,a2=0,a3=0;
    {
      const float* wr = W_lds + r*WSTR + l*4;
      const float* hr = h_lds + l*4;
#pragma unroll
      for(int kk=0; kk<16; ++kk){
        float4 wv = *(const float4*)(wr + kk*64);
        float4 hv = *(const float4*)(hr + kk*64);
        a0 = fmaf(wv.x, hv.x, a0);
        a1 = fmaf(wv.y, hv.y, a1);
        a2 = fmaf(wv.z, hv.z, a2);
        a3 = fmaf(wv.w, hv.w, a3);
      }
    }
    float acc = (a0+a1)+(a2+a3);
    acc += __shfl_xor(acc,1); acc += __shfl_xor(acc,2);
    acc += __shfl_xor(acc,4); acc += __shfl_xor(acc,8);
    if(l==0) gbuf[r] = acc + pre_dec[(size_t)t*G4 + (r>>2)*HID + u4 + (r&3)];
    __syncthreads();
    if(tid<4){
      float gi=gbuf[tid], gf=gbuf[4+tid], gg=gbuf[8+tid], go=gbuf[12+tid];
      float cn = sigm(gf)*creg + sigm(gi)*tanhf(gg);
      float hn = sigm(go)*tanhf(cn);
      creg = cn;
      Hdec[(size_t)t*HID + u4 + tid] = hn;
      pub_val(&h_tag[((t+1)&1)*HID + u4+tid], hn, DECTAG + (unsigned)(t+1));
    }
    __syncthreads();
  }
}

// ---------------- in-place log_softmax + first-index argmax ----------------
__global__ __launch_bounds__(256) void softmax_argmax(float* __restrict__ dist,
                                                      float* __restrict__ outTok)
{
  __shared__ float wm[4]; __shared__ int wi[4];
  __shared__ float s_max; __shared__ int s_idx; __shared__ float s_lz;
  const int t = blockIdx.x, tid = threadIdx.x;
  float* row = dist + (size_t)t*VOCAB;
  float m = -INFINITY; int idx = VOCAB;
  for(int i=tid; i<VOCAB; i+=256){
    float v = row[i];
    if(v > m){ m = v; idx = i; }
  }
  for(int d=1; d<64; d<<=1){
    float m2 = __shfl_xor(m, d); int i2 = __shfl_xor(idx, d);
    if(m2 > m || (m2 == m && i2 < idx)){ m = m2; idx = i2; }
  }
  if((tid&63)==0){ wm[tid>>6]=m; wi[tid>>6]=idx; }
  __syncthreads();
  if(tid==0){
    float mm = wm[0]; int ii = wi[0];
    for(int q=1;q<4;++q) if(wm[q]>mm || (wm[q]==mm && wi[q]<ii)){ mm=wm[q]; ii=wi[q]; }
    s_max = mm; s_idx = ii;
  }
  __syncthreads();
  const float M = s_max;
  float s = 0.f;
  for(int i=tid; i<VOCAB; i+=256) s += expf(row[i] - M);
  for(int d=1; d<64; d<<=1) s += __shfl_xor(s, d);
  if((tid&63)==0) wm[tid>>6] = s;
  __syncthreads();
  if(tid==0) s_lz = M + logf(wm[0]+wm[1]+wm[2]+wm[3]);
  __syncthreads();
  const float lz = s_lz;
  for(int i=tid; i<VOCAB; i+=256) row[i] -= lz;
  if(tid==0) outTok[t] = (float)s_idx;
}

// ---------------- launch ----------------
extern "C" void kernel_launch(void* const* d_in, const int* in_sizes, int n_in,
                              void* d_out, int out_size, void* d_ws, size_t ws_size,
                              hipStream_t stream)
{
  (void)in_sizes; (void)n_in; (void)out_size; (void)ws_size;
  const int*   tok      = (const int*)  d_in[0];
  const float* h0       = (const float*)d_in[1];
  const float* c0       = (const float*)d_in[2];
  const float* ccond    = (const float*)d_in[3];
  // d_in[4] = use_teacher_forcing (unused by reference body)
  const float* enc_emb  = (const float*)d_in[5];
  const float* enc_Wih  = (const float*)d_in[6];
  const float* enc_Whh  = (const float*)d_in[7];
  const float* enc_bih  = (const float*)d_in[8];
  const float* enc_bhh  = (const float*)d_in[9];
  const float* dec_emb  = (const float*)d_in[10];
  const float* dec_Wih  = (const float*)d_in[11];
  const float* dec_Whh  = (const float*)d_in[12];
  const float* dec_bih  = (const float*)d_in[13];
  const float* dec_bhh  = (const float*)d_in[14];
  const float* out_W    = (const float*)d_in[15];
  const float* out_b    = (const float*)d_in[16];
  const float* mean_W   = (const float*)d_in[17];
  const float* mean_b   = (const float*)d_in[18];
  const float* logvar_W = (const float*)d_in[19];
  const float* logvar_b = (const float*)d_in[20];
  const float* lc_W     = (const float*)d_in[21];
  const float* lc_b     = (const float*)d_in[22];

  float* ws      = (float*)d_ws;
  float* xenc    = ws;                       // 256*1024
  float* xdec    = xenc + SEQ*HID;           // 256*1024
  float* pre_enc = xdec + SEQ*HID;           // 256*4096
  float* pre_dec = pre_enc + (size_t)SEQ*G4; // 256*4096
  float* Hdec    = pre_dec + (size_t)SEQ*G4; // 256*1024
  ull*   tags    = (ull*)(Hdec + (size_t)SEQ*HID);  // 8B-aligned (offset = 11.5MB)
  ull*   h_tag   = tags;                     // [2*1024]
  ull*   mlv_tag = h_tag + 2*HID;            // [256]
  ull*   lat_tag = mlv_tag + 2*LZD;          // [160]
  // total ~11.6 MB of ws

  float* out      = (float*)d_out;
  float* outTok   = out;                          // [256] tokens (as f32)
  float* dist     = out + SEQ;                    // [256,50257] log-softmax
  float* out_mean = dist + (size_t)SEQ*VOCAB;     // [128]
  float* out_lv   = out_mean + LZD;               // [128]

  hipLaunchKernelGGL(vae_embed, dim3(SEQ+1), dim3(256), 0, stream,
                     tok, enc_emb, dec_emb, xenc, xdec, tags);
  hipLaunchKernelGGL(gemm_nt_bias, dim3(G4/64, SEQ/64), dim3(256), 0, stream,
                     xenc, enc_Wih, enc_bih, enc_bhh, pre_enc, HID, G4);
  hipLaunchKernelGGL(gemm_nt_bias, dim3(G4/64, SEQ/64), dim3(256), 0, stream,
                     xdec, dec_Wih, dec_bih, dec_bhh, pre_dec, HID, G4);
  hipLaunchKernelGGL(vae_scan, dim3(NWG), dim3(256), 0, stream,
                     enc_Whh, dec_Whh, pre_enc, pre_dec, h0, c0, ccond,
                     mean_W, mean_b, logvar_W, logvar_b, lc_W, lc_b,
                     h_tag, mlv_tag, lat_tag, Hdec, out_mean, out_lv);
  hipLaunchKernelGGL(gemm_nt_bias, dim3((VOCAB+63)/64, SEQ/64), dim3(256), 0, stream,
                     Hdec, out_W, out_b, (const float*)nullptr, dist, HID, VOCAB);
  hipLaunchKernelGGL(softmax_argmax, dim3(SEQ), dim3(256), 0, stream, dist, outTok);
}